// Round 1
// baseline (453.294 us; speedup 1.0000x reference)
//
#include <hip/hip_runtime.h>
#include <math.h>

// Problem constants (B=4, S=4096, H=4096, E=64, top_k=8)
#define H_DIM  4096
#define E_NUM  64
#define N_TOK  16384          // B*S
#define TPB    64             // tokens per block
#define KC     64             // K chunk
#define NCHUNK (H_DIM / KC)   // 64
#define TOPK   8

// flat output layout: [probs (N_TOK*64)][indices (N_TOK*8)][gate (N_TOK*64)]
#define N_PROBS  (N_TOK * E_NUM)          // 1048576
#define N_IDX    (N_TOK * TOPK)           // 131072
#define OFF_IDX  N_PROBS
#define OFF_GATE (N_PROBS + N_IDX)        // 1179648

__global__ __launch_bounds__(256, 1)
void gating_kernel(const float* __restrict__ x, const float* __restrict__ W,
                   float* __restrict__ out) {
  // LDS: x-tile double buffer unioned with the epilogue logits scratch.
  // k-major tiles: rows are 64 floats (=2x32 banks) so both the transposed
  // scalar stores (banks = token%32, 2-way) and the b128 fragment reads
  // (row-contiguous) are conflict-free. Total 65536 B.
  __shared__ union {
    float xs[2][KC][TPB];          // 32 KB, [buf][k][token]
    float lg[TPB][E_NUM + 1];      // 16.6 KB, stride 65 breaks phase-2 conflicts
  } u;
  __shared__ float ws[2][KC][E_NUM]; // 32 KB, [buf][k][expert]

  const int tid  = threadIdx.x;
  const int tok0 = blockIdx.x * TPB;
  const int tx   = tid & 15;   // expert group: experts 4*tx..4*tx+3
  const int ty   = tid >> 4;   // token group:  tokens 4*ty..4*ty+3

  const float* xg = x + (size_t)tok0 * H_DIM;

  float4 xr[4], wr[4];

  // 64x64 tile load: f4 = tid+256p -> row = f4&63 (token/expert), kq = f4>>6.
  // Per wave: 64 rows x 16 B (L1 absorbs across the 4 passes).
  auto gload = [&](int kb) {
#pragma unroll
    for (int p = 0; p < 4; ++p) {
      const int f4  = tid + 256 * p;
      const int row = f4 & 63;
      const int kq  = f4 >> 6;
      xr[p] = *(const float4*)(xg + row * H_DIM + kb + 4 * kq);
      wr[p] = *(const float4*)(W  + row * H_DIM + kb + 4 * kq);
    }
  };
  // transposed store into k-major LDS tiles (4 scalar writes, 2-way banks = free)
  auto sstore = [&](int b) {
#pragma unroll
    for (int p = 0; p < 4; ++p) {
      const int f4  = tid + 256 * p;
      const int row = f4 & 63;
      const int k0  = (f4 >> 6) << 2;
      u.xs[b][k0 + 0][row] = xr[p].x;
      u.xs[b][k0 + 1][row] = xr[p].y;
      u.xs[b][k0 + 2][row] = xr[p].z;
      u.xs[b][k0 + 3][row] = xr[p].w;
      ws[b][k0 + 0][row] = wr[p].x;
      ws[b][k0 + 1][row] = wr[p].y;
      ws[b][k0 + 2][row] = wr[p].z;
      ws[b][k0 + 3][row] = wr[p].w;
    }
  };

  gload(0);
  sstore(0);
  __syncthreads();

  // fp64 cross-chunk accumulation keeps |ours - np_fp32_ref| ~2e-7 so the
  // top-8 ranking (the only tight output) matches the reference.
  double accd[4][4];
#pragma unroll
  for (int i = 0; i < 4; ++i)
#pragma unroll
    for (int j = 0; j < 4; ++j) accd[i][j] = 0.0;

  for (int c = 0; c < NCHUNK; ++c) {
    if (c + 1 < NCHUNK) gload((c + 1) * KC);   // prefetch next chunk to regs
    const int b = c & 1;

    float ca[4][4];
#pragma unroll
    for (int i = 0; i < 4; ++i)
#pragma unroll
      for (int j = 0; j < 4; ++j) ca[i][j] = 0.f;

#pragma unroll 8
    for (int k = 0; k < KC; ++k) {
      const float4 av = *(const float4*)&u.xs[b][k][4 * ty];
      const float4 bv = *(const float4*)&ws[b][k][4 * tx];
      const float a[4]  = {av.x, av.y, av.z, av.w};
      const float bb[4] = {bv.x, bv.y, bv.z, bv.w};
#pragma unroll
      for (int i = 0; i < 4; ++i)
#pragma unroll
        for (int j = 0; j < 4; ++j)
          ca[i][j] = fmaf(a[i], bb[j], ca[i][j]);
    }
#pragma unroll
    for (int i = 0; i < 4; ++i)
#pragma unroll
      for (int j = 0; j < 4; ++j) accd[i][j] += (double)ca[i][j];

    if (c + 1 < NCHUNK) {
      // writes go to buffer (c+1)&1, whose last readers finished before the
      // barrier that ended iteration c-1 -> one barrier per chunk suffices.
      sstore((c + 1) & 1);
      __syncthreads();
    }
  }

  float acc[4][4];
#pragma unroll
  for (int i = 0; i < 4; ++i)
#pragma unroll
    for (int j = 0; j < 4; ++j) acc[i][j] = (float)accd[i][j];

  // gate_logit: coalesced float4 stores (registers -> global, no LDS needed)
  float* gate = out + OFF_GATE;
#pragma unroll
  for (int i = 0; i < 4; ++i) {
    const int t = 4 * ty + i;
    float4 v = make_float4(acc[i][0], acc[i][1], acc[i][2], acc[i][3]);
    *(float4*)(gate + (size_t)(tok0 + t) * E_NUM + 4 * tx) = v;
  }

  __syncthreads();             // all waves done reading u.xs before aliasing
#pragma unroll
  for (int i = 0; i < 4; ++i)
#pragma unroll
    for (int j = 0; j < 4; ++j)
      u.lg[4 * ty + i][4 * tx + j] = acc[i][j];
  __syncthreads();

  // Phase 2: one thread per token (wave 0 only; epilogue is ~2% of runtime).
  if (tid < TPB) {
    const int t = tid;
    float vals[TOPK];
    int   idxs[TOPK];
#pragma unroll
    for (int p = 0; p < TOPK; ++p) {
      float best = -INFINITY;
      int   bi   = 0;
      for (int e = 0; e < E_NUM; ++e) {
        const float v = u.lg[t][e];
        if (v > best) { best = v; bi = e; }   // strict > == jax lowest-index tie-break
      }
      vals[p] = best;
      idxs[p] = bi;
      u.lg[t][bi] = -INFINITY;
    }
    // softmax over the selected 8 (masked softmax: others are exactly 0)
    const float m = vals[0];
    float s = 0.f, pr[TOPK];
#pragma unroll
    for (int p = 0; p < TOPK; ++p) { pr[p] = __expf(vals[p] - m); s += pr[p]; }
    const float inv = 1.0f / s;
    for (int e = 0; e < E_NUM; ++e) u.lg[t][e] = 0.f;
#pragma unroll
    for (int p = 0; p < TOPK; ++p) u.lg[t][idxs[p]] = pr[p] * inv;

    // indices: flat out buffer is fp32 -> write as float (exact for 0..63)
    float* oidx = out + OFF_IDX + (size_t)(tok0 + t) * TOPK;
#pragma unroll
    for (int p = 0; p < TOPK; ++p) oidx[p] = (float)idxs[p];
  }
  __syncthreads();

  // coalesced writeback of the sparse_probs rows
  float* oprob = out + (size_t)tok0 * E_NUM;
#pragma unroll
  for (int p = 0; p < 16; ++p) {
    const int f = tid + 256 * p;
    oprob[f] = u.lg[f >> 6][f & 63];
  }
}

extern "C" void kernel_launch(void* const* d_in, const int* in_sizes, int n_in,
                              void* d_out, int out_size, void* d_ws, size_t ws_size,
                              hipStream_t stream) {
  const float* x = (const float*)d_in[0];
  const float* W = (const float*)d_in[1];
  float* out = (float*)d_out;
  dim3 grid(N_TOK / TPB);   // 256 blocks -> 1 per CU
  dim3 block(256);
  gating_kernel<<<grid, block, 0, stream>>>(x, W, out);
}